// Round 1
// baseline (1603.387 us; speedup 1.0000x reference)
//
#include <hip/hip_runtime.h>
#include <hip/hip_fp16.h>

// AdaAttN fused pipeline, fp16 MFMA path.
// B=8, C=512, Tc=8192, Ts=2048.
//
// ws layout (bytes):
//   Ft  [8][8192][512] fp16 :      0 .. 67,108,864
//   Gt  [8][2048][512] fp16 : 67,108,864 .. 83,886,080
//   H   [8][512][2048] fp16 : 83,886,080 .. 100,663,296
//   cmean [4096] f32        : 100,663,296
//   crstd [4096] f32        : 100,679,680
// total ~96 MB.

#define B_ 8
#define C_ 512
#define TC 8192
#define TS 2048

typedef unsigned short u16;
typedef __attribute__((ext_vector_type(8))) _Float16 f16x8;
typedef __attribute__((ext_vector_type(4))) float f32x4;

__device__ __forceinline__ u16 f2h(float f) {
  return __half_as_ushort(__float2half(f));
}

__device__ __forceinline__ f32x4 mfma16(f16x8 a, f16x8 b, f32x4 c) {
  return __builtin_amdgcn_mfma_f32_16x16x32_f16(a, b, c, 0, 0, 0);
}

// ---------------- K0: per-(b,c) content stats (ddof=1) ----------------
__global__ __launch_bounds__(256) void k_content_stats(
    const float* __restrict__ x, float* __restrict__ cmean, float* __restrict__ crstd) {
  const int row = blockIdx.x;  // b*512 + c
  const float4* p = (const float4*)(x + (size_t)row * TC);
  float s = 0.f, ss = 0.f;
  for (int i = threadIdx.x; i < TC / 4; i += 256) {
    float4 v = p[i];
    s += v.x + v.y + v.z + v.w;
    ss += v.x * v.x + v.y * v.y + v.z * v.z + v.w * v.w;
  }
#pragma unroll
  for (int d = 1; d < 64; d <<= 1) {
    s += __shfl_xor(s, d);
    ss += __shfl_xor(ss, d);
  }
  __shared__ float rs[4], rss[4];
  if ((threadIdx.x & 63) == 0) {
    rs[threadIdx.x >> 6] = s;
    rss[threadIdx.x >> 6] = ss;
  }
  __syncthreads();
  if (threadIdx.x == 0) {
    float S = rs[0] + rs[1] + rs[2] + rs[3];
    float SS = rss[0] + rss[1] + rss[2] + rss[3];
    float mean = S / (float)TC;
    float var = (SS - S * mean) / (float)(TC - 1);
    cmean[row] = mean;
    crstd[row] = rsqrtf(var + 1e-5f);
  }
}

// ---------------- conv1x1 GEMM: Y[m][n] = sum_k X[k][m] * W[n][k] + bias[n] ----
// X: [B][512][M] f32 (A, transpose-staged), W: [512][512] f32 (B operand, K-inner)
// TRANS_OUT=false: Y[b][m][n] fp16 ;  TRANS_OUT=true: Y[b][n][m] fp16
// Tiles: BM=32, BN=256, BK=64; 4 waves; wave w owns n-range w*64.
template <bool TRANS_OUT>
__global__ __launch_bounds__(256, 3) void k_conv(
    const float* __restrict__ X, const float* __restrict__ W,
    const float* __restrict__ bias, u16* __restrict__ Y, int M) {
  const int b = blockIdx.z;
  const int m0 = blockIdx.x * 32;
  const int n0 = blockIdx.y * 256;
  const int tid = threadIdx.x;
  const int w = tid >> 6, ln = tid & 63, g = ln >> 4, l15 = ln & 15;
  __shared__ u16 As[32][72];
  __shared__ u16 Bs[256][72];
  const float* Xb = X + (size_t)b * C_ * M;
  const f32x4 vzero = {0.f, 0.f, 0.f, 0.f};
  f32x4 acc[2][4];
#pragma unroll
  for (int i = 0; i < 2; ++i)
#pragma unroll
    for (int j = 0; j < 4; ++j) acc[i][j] = vzero;

  for (int k0 = 0; k0 < 512; k0 += 64) {
    __syncthreads();
    {  // stage A: X[k0..+64][m0..+32] -> As[m][k] (transpose + cvt)
      const int kk = tid >> 2, c4 = tid & 3;
      const float* src = Xb + (size_t)(k0 + kk) * M + m0;
#pragma unroll
      for (int i = 0; i < 2; ++i) {
        const int mo = c4 * 4 + i * 16;
        float4 v = *(const float4*)(src + mo);
        As[mo + 0][kk] = f2h(v.x);
        As[mo + 1][kk] = f2h(v.y);
        As[mo + 2][kk] = f2h(v.z);
        As[mo + 3][kk] = f2h(v.w);
      }
    }
    {  // stage B: W[n0..+256][k0..+64] -> Bs[n][k]
      const float* src = W + (size_t)(n0 + tid) * 512 + k0;
#pragma unroll
      for (int i = 0; i < 16; ++i) {
        float4 v = *(const float4*)(src + i * 4);
        ushort4 h = make_ushort4(f2h(v.x), f2h(v.y), f2h(v.z), f2h(v.w));
        *(ushort4*)&Bs[tid][i * 4] = h;
      }
    }
    __syncthreads();
#pragma unroll
    for (int ks = 0; ks < 2; ++ks) {
      f16x8 a[2], bb[4];
#pragma unroll
      for (int mt = 0; mt < 2; ++mt)
        a[mt] = *(const f16x8*)&As[mt * 16 + l15][ks * 32 + g * 8];
#pragma unroll
      for (int nt = 0; nt < 4; ++nt)
        bb[nt] = *(const f16x8*)&Bs[w * 64 + nt * 16 + l15][ks * 32 + g * 8];
#pragma unroll
      for (int mt = 0; mt < 2; ++mt)
#pragma unroll
        for (int nt = 0; nt < 4; ++nt)
          acc[mt][nt] = mfma16(a[mt], bb[nt], acc[mt][nt]);
    }
  }
  // epilogue: C row = (lane>>4)*4 + reg (+16*mt), col = lane&15 (+16*nt +64*w)
#pragma unroll
  for (int nt = 0; nt < 4; ++nt) {
    const int n = n0 + w * 64 + nt * 16 + l15;
    const float bv = bias[n];
#pragma unroll
    for (int mt = 0; mt < 2; ++mt) {
      const int mb = m0 + mt * 16 + g * 4;
      f32x4 v = acc[mt][nt];
      if (!TRANS_OUT) {
        u16* yp = Y + (size_t)b * M * 512 + (size_t)mb * 512 + n;
        yp[0 * 512] = f2h(v[0] + bv);
        yp[1 * 512] = f2h(v[1] + bv);
        yp[2 * 512] = f2h(v[2] + bv);
        yp[3 * 512] = f2h(v[3] + bv);
      } else {
        ushort4 h = make_ushort4(f2h(v[0] + bv), f2h(v[1] + bv),
                                 f2h(v[2] + bv), f2h(v[3] + bv));
        *(ushort4*)(Y + (size_t)b * 512 * M + (size_t)n * M + mb) = h;
      }
    }
  }
}

// ---------------- K5: fused attention + AdaAttN epilogue ----------------
// block = 512 thr (8 waves), handles (b, 64 query rows t0..t0+64).
// Two passes over s (stats then apply); wave w owns score cols w*32..+32 of each
// 256-wide supertile, and c-range w*64..+64 for PV.
struct alignas(16) SmemAttn {
  u16 Fq[64 * 520];  // A tile [64 t][512 c], padded stride 520
  union {
    u16 Gs[256 * 72];  // score B tile [256 s][64 k]
    u16 Hs[512 * 40];  // PV B tile [512 c][32 s]
  } u;
  u16 Ps[64 * 264];  // P tile [64 t][256 s]
  float redm[64][8];
  float redl[64][8];
  float fin[64][2];
};  // ~145.9 KB

__global__ __launch_bounds__(512, 2) void k_attn(
    const u16* __restrict__ Ft, const u16* __restrict__ Gt,
    const u16* __restrict__ Hm, const float* __restrict__ content,
    const float* __restrict__ cmean, const float* __restrict__ crstd,
    float* __restrict__ out) {
  __shared__ SmemAttn sm;
  const int b = blockIdx.y;
  const int t0 = blockIdx.x * 64;
  const int tid = threadIdx.x;
  const int w = tid >> 6, ln = tid & 63, g = ln >> 4, l15 = ln & 15;

  const u16* Ftb = Ft + ((size_t)b * TC + t0) * C_;
  const u16* Gtb = Gt + (size_t)b * TS * C_;
  const u16* Hb = Hm + (size_t)b * C_ * TS;

  {  // stage Fq once (A operand for both score passes)
    const int r = tid >> 3, c0 = tid & 7;
#pragma unroll
    for (int i = 0; i < 8; ++i) {
      const int ch = c0 + 8 * i;
      *(uint4*)&sm.Fq[r * 520 + ch * 8] = *(const uint4*)(Ftb + (size_t)r * C_ + ch * 8);
    }
  }

  // scores for this wave's [64 q][32 s] block at supertile base `sbase`
  auto score_block = [&](int sbase, f32x4(&sacc)[4][2]) {
    const f32x4 vzero = {0.f, 0.f, 0.f, 0.f};
#pragma unroll
    for (int mt = 0; mt < 4; ++mt)
#pragma unroll
      for (int nt = 0; nt < 2; ++nt) sacc[mt][nt] = vzero;
    for (int kc = 0; kc < 8; ++kc) {
      __syncthreads();
      {  // stage Gs [256 s][64 k]
        const int s = tid >> 1, h = tid & 1;
        const u16* srow = Gtb + (size_t)(sbase + s) * C_ + kc * 64;
#pragma unroll
        for (int i = 0; i < 4; ++i) {
          const int ch = h + 2 * i;
          *(uint4*)&sm.u.Gs[s * 72 + ch * 8] = *(const uint4*)(srow + ch * 8);
        }
      }
      __syncthreads();
#pragma unroll
      for (int ks = 0; ks < 2; ++ks) {
        f16x8 a[4], bb[2];
#pragma unroll
        for (int mt = 0; mt < 4; ++mt)
          a[mt] = *(const f16x8*)&sm.Fq[(mt * 16 + l15) * 520 + kc * 64 + ks * 32 + g * 8];
#pragma unroll
        for (int nt = 0; nt < 2; ++nt)
          bb[nt] = *(const f16x8*)&sm.u.Gs[(w * 32 + nt * 16 + l15) * 72 + ks * 32 + g * 8];
#pragma unroll
        for (int mt = 0; mt < 4; ++mt)
#pragma unroll
          for (int nt = 0; nt < 2; ++nt)
            sacc[mt][nt] = mfma16(a[mt], bb[nt], sacc[mt][nt]);
      }
    }
  };

  // ---- stats pass: per-row online max/denominator over this wave's cols ----
  float mw[4][4], lw[4][4];
#pragma unroll
  for (int mt = 0; mt < 4; ++mt)
#pragma unroll
    for (int rg = 0; rg < 4; ++rg) {
      mw[mt][rg] = -1e30f;
      lw[mt][rg] = 0.f;
    }
  for (int st = 0; st < 8; ++st) {
    f32x4 sacc[4][2];
    score_block(st * 256, sacc);
#pragma unroll
    for (int mt = 0; mt < 4; ++mt)
#pragma unroll
      for (int rg = 0; rg < 4; ++rg) {
        float v0 = sacc[mt][0][rg], v1 = sacc[mt][1][rg];
        float mx = fmaxf(v0, v1);
        mx = fmaxf(mx, __shfl_xor(mx, 1));
        mx = fmaxf(mx, __shfl_xor(mx, 2));
        mx = fmaxf(mx, __shfl_xor(mx, 4));
        mx = fmaxf(mx, __shfl_xor(mx, 8));
        const float mn = fmaxf(mw[mt][rg], mx);
        float sum = __expf(v0 - mn) + __expf(v1 - mn);
        sum += __shfl_xor(sum, 1);
        sum += __shfl_xor(sum, 2);
        sum += __shfl_xor(sum, 4);
        sum += __shfl_xor(sum, 8);
        lw[mt][rg] = lw[mt][rg] * __expf(mw[mt][rg] - mn) + sum;
        mw[mt][rg] = mn;
      }
  }
  if (l15 == 0) {
#pragma unroll
    for (int mt = 0; mt < 4; ++mt)
#pragma unroll
      for (int rg = 0; rg < 4; ++rg) {
        const int r = mt * 16 + g * 4 + rg;
        sm.redm[r][w] = mw[mt][rg];
        sm.redl[r][w] = lw[mt][rg];
      }
  }
  __syncthreads();
  if (tid < 64) {
    float m = -1e30f;
#pragma unroll
    for (int j = 0; j < 8; ++j) m = fmaxf(m, sm.redm[tid][j]);
    float l = 0.f;
#pragma unroll
    for (int j = 0; j < 8; ++j) l += sm.redl[tid][j] * __expf(sm.redm[tid][j] - m);
    sm.fin[tid][0] = m;
    sm.fin[tid][1] = 1.f / l;
  }
  __syncthreads();

  // ---- apply pass: P = exp(score-m)/l ; mean += P*H ; second += P*H^2 ----
  const f32x4 vzero = {0.f, 0.f, 0.f, 0.f};
  f32x4 pvm[4][4], pvs[4][4];
#pragma unroll
  for (int mt = 0; mt < 4; ++mt)
#pragma unroll
    for (int nt = 0; nt < 4; ++nt) {
      pvm[mt][nt] = vzero;
      pvs[mt][nt] = vzero;
    }

  for (int st = 0; st < 8; ++st) {
    f32x4 sacc[4][2];
    score_block(st * 256, sacc);
#pragma unroll
    for (int mt = 0; mt < 4; ++mt)
#pragma unroll
      for (int rg = 0; rg < 4; ++rg) {
        const int r = mt * 16 + g * 4 + rg;
        const float mf = sm.fin[r][0], rl = sm.fin[r][1];
        sm.Ps[r * 264 + w * 32 + 0 + l15] = f2h(__expf(sacc[mt][0][rg] - mf) * rl);
        sm.Ps[r * 264 + w * 32 + 16 + l15] = f2h(__expf(sacc[mt][1][rg] - mf) * rl);
      }
    for (int ksl = 0; ksl < 8; ++ksl) {
      __syncthreads();  // Ps visible (iter 0) / prior Hs+Gs reads done
      {                 // stage Hs [512 c][32 s]
        const int ch = tid & 3, cr = tid >> 2;
        const int s0 = st * 256 + ksl * 32;
#pragma unroll
        for (int j = 0; j < 4; ++j) {
          const int c = cr + 128 * j;
          *(uint4*)&sm.u.Hs[c * 40 + ch * 8] = *(const uint4*)(Hb + (size_t)c * TS + s0 + ch * 8);
        }
      }
      __syncthreads();
      f16x8 pa[4];
#pragma unroll
      for (int mt = 0; mt < 4; ++mt)
        pa[mt] = *(const f16x8*)&sm.Ps[(mt * 16 + l15) * 264 + ksl * 32 + g * 8];
#pragma unroll
      for (int nt = 0; nt < 4; ++nt) {
        f16x8 hv = *(const f16x8*)&sm.u.Hs[(w * 64 + nt * 16 + l15) * 40 + g * 8];
        f16x8 h2 = hv * hv;
#pragma unroll
        for (int mt = 0; mt < 4; ++mt) {
          pvm[mt][nt] = mfma16(pa[mt], hv, pvm[mt][nt]);
          pvs[mt][nt] = mfma16(pa[mt], h2, pvs[mt][nt]);
        }
      }
    }
  }

  // ---- epilogue: out[b][c][t] = std * (content - cmean)*crstd + mean ----
#pragma unroll
  for (int nt = 0; nt < 4; ++nt) {
    const int c = w * 64 + nt * 16 + l15;
    const size_t row = (size_t)b * C_ + c;
    const float cm = cmean[row];
    const float cr = crstd[row];
    const float* cp = content + row * TC + t0;
    float* op = out + row * TC + t0;
#pragma unroll
    for (int mt = 0; mt < 4; ++mt) {
      const int q0 = mt * 16 + g * 4;
      const float4 x = *(const float4*)(cp + q0);
      const f32x4 mu = pvm[mt][nt];
      const f32x4 se = pvs[mt][nt];
      float4 y;
      y.x = sqrtf(fmaxf(se[0] - mu[0] * mu[0], 0.f)) * ((x.x - cm) * cr) + mu[0];
      y.y = sqrtf(fmaxf(se[1] - mu[1] * mu[1], 0.f)) * ((x.y - cm) * cr) + mu[1];
      y.z = sqrtf(fmaxf(se[2] - mu[2] * mu[2], 0.f)) * ((x.z - cm) * cr) + mu[2];
      y.w = sqrtf(fmaxf(se[3] - mu[3] * mu[3], 0.f)) * ((x.w - cm) * cr) + mu[3];
      *(float4*)(op + q0) = y;
    }
  }
}

extern "C" void kernel_launch(void* const* d_in, const int* in_sizes, int n_in,
                              void* d_out, int out_size, void* d_ws, size_t ws_size,
                              hipStream_t stream) {
  (void)in_sizes;
  (void)n_in;
  (void)out_size;
  (void)ws_size;  // needs ~96 MB
  const float* content = (const float*)d_in[0];
  const float* style = (const float*)d_in[1];
  const float* content_key = (const float*)d_in[2];
  const float* style_key = (const float*)d_in[3];
  const float* Wf = (const float*)d_in[4];
  const float* bf = (const float*)d_in[5];
  const float* Wg = (const float*)d_in[6];
  const float* bg = (const float*)d_in[7];
  const float* Wh = (const float*)d_in[8];
  const float* bh = (const float*)d_in[9];
  float* out = (float*)d_out;

  char* ws = (char*)d_ws;
  u16* Ft = (u16*)(ws);
  u16* Gt = (u16*)(ws + 67108864);
  u16* Hm = (u16*)(ws + 83886080);
  float* cmean = (float*)(ws + 100663296);
  float* crstd = (float*)(ws + 100663296 + 16384);

  k_content_stats<<<dim3(B_ * C_), dim3(256), 0, stream>>>(content, cmean, crstd);
  // Ft[b][t][c] = sum_k content_key[b][k][t] * Wf[c][k] + bf[c]
  k_conv<false><<<dim3(TC / 32, 2, B_), dim3(256), 0, stream>>>(content_key, Wf, bf, Ft, TC);
  // Gt[b][s][c] = sum_k style_key[b][k][s] * Wg[c][k] + bg[c]
  k_conv<false><<<dim3(TS / 32, 2, B_), dim3(256), 0, stream>>>(style_key, Wg, bg, Gt, TS);
  // H[b][c][s] = sum_k style[b][k][s] * Wh[c][k] + bh[c]   (transposed store)
  k_conv<true><<<dim3(TS / 32, 2, B_), dim3(256), 0, stream>>>(style, Wh, bh, Hm, TS);

  k_attn<<<dim3(TC / 64, B_), dim3(512), 0, stream>>>(Ft, Gt, Hm, content, cmean, crstd, out);
}